// Round 6
// baseline (107.354 us; speedup 1.0000x reference)
//
#include <hip/hip_runtime.h>

#define VV 8
#define JJ 64
#define THR 400.0f
#define ALPHA 0.1f
#define NB 2048      // blocks
#define BITER 2      // batch elements per wave

// ---------------------------------------------------------------------------
// Fused kernel. Each wave owns one batch element b per iteration:
//   - stage R[b], t[b], C[b] into wave-private LDS (coalesced stride-1 loads)
//   - lanes 0..47 fold one row each of M = K@[R|t], N = K@C (float4)
//   - all lanes: project keypoint j=lane through all 8 views, smooth-MSE
// No __syncthreads in the hot loop: all LDS traffic is wave-private, and the
// DS pipe processes a wave's ops in order (wave_barrier fences compiler
// reordering).
// ---------------------------------------------------------------------------
__global__ __launch_bounds__(256) void proj_loss_kernel(
    const float* __restrict__ kps_gt,    // [B,J,3]
    const float* __restrict__ kps_pred,  // [B,J,3]
    const float* __restrict__ gt_R,      // [B,V,3,3]
    const float* __restrict__ gt_t,      // [B,V,3]
    const float* __restrict__ Kmat,      // [V,3,3]
    const float* __restrict__ cam,       // [B,V,3,4]
    float* __restrict__ partials)        // [NB]
{
    __shared__ float  s_K[VV * 9];        // 288 B, block-shared (read-only)
    __shared__ float  s_stage[4][192];    // wave-private staging: R|t|C
    __shared__ float4 s_MN[4][48];        // wave-private folded rows
    __shared__ float  s_red[4];

    const int tid  = threadIdx.x;
    const int lane = tid & 63;
    const int w    = tid >> 6;

    if (tid < VV * 9) s_K[tid] = Kmat[tid];
    __syncthreads();  // publish K to all waves (once)

    // Fold-lane constants (lane < 48 folds row fr of M (fwhich=0) or N (1) of view fv)
    const int fv    = lane / 6;
    const int fidx  = lane - fv * 6;
    const int fwhich = (fidx >= 3) ? 1 : 0;
    const int fr    = fidx - 3 * fwhich;
    float k0 = 0.f, k1 = 0.f, k2 = 0.f;
    if (lane < 48) {
        k0 = s_K[fv * 9 + fr * 3 + 0];
        k1 = s_K[fv * 9 + fr * 3 + 1];
        k2 = s_K[fv * 9 + fr * 3 + 2];
    }

    float*  stg = s_stage[w];
    float4* mn  = s_MN[w];
    const float c09 = powf(THR, 0.9f);  // compile-time constant

    float acc = 0.0f;

#pragma unroll
    for (int it = 0; it < BITER; ++it) {
        const int b = blockIdx.x * (4 * BITER) + it * 4 + w;

        // ---- stage R|t|C into wave-private LDS (stride-1 coalesced) ----
        const float* Rb = gt_R + (size_t)b * 72;
        const float* tb = gt_t + (size_t)b * 24;
        const float* Cb = cam  + (size_t)b * 96;
        stg[lane] = Rb[lane];
        if (lane < 8)  stg[64 + lane] = Rb[64 + lane];
        if (lane < 24) stg[72 + lane] = tb[lane];
        stg[96 + lane] = Cb[lane];
        if (lane < 32) stg[160 + lane] = Cb[64 + lane];

        // per-lane keypoints (j = lane) — straight to registers
        const float* g = kps_gt   + (size_t)b * (JJ * 3) + lane * 3;
        const float* p = kps_pred + (size_t)b * (JJ * 3) + lane * 3;
        const float X0 = g[0], X1 = g[1], X2 = g[2];
        const float P0 = p[0], P1 = p[1], P2 = p[2];

        __builtin_amdgcn_wave_barrier();  // fence: stage writes before fold reads

        // ---- fold: M = K@[R|t], N = K@C  (lanes 0..47, one float4 row each)
        if (lane < 48) {
            float4 o;
            if (!fwhich) {
                const float* R = &stg[fv * 9];
                const float* t = &stg[72 + fv * 3];
                o.x = fmaf(k0, R[0], fmaf(k1, R[3], k2 * R[6]));
                o.y = fmaf(k0, R[1], fmaf(k1, R[4], k2 * R[7]));
                o.z = fmaf(k0, R[2], fmaf(k1, R[5], k2 * R[8]));
                o.w = fmaf(k0, t[0], fmaf(k1, t[1], k2 * t[2]));
            } else {
                const float* C = &stg[96 + fv * 12];
                o.x = fmaf(k0, C[0], fmaf(k1, C[4], k2 * C[8]));
                o.y = fmaf(k0, C[1], fmaf(k1, C[5], k2 * C[9]));
                o.z = fmaf(k0, C[2], fmaf(k1, C[6], k2 * C[10]));
                o.w = fmaf(k0, C[3], fmaf(k1, C[7], k2 * C[11]));
            }
            mn[fv * 6 + fwhich * 3 + fr] = o;
        }

        __builtin_amdgcn_wave_barrier();  // fence: fold writes before compute reads

        // ---- compute: project keypoint through all 8 views ----
#pragma unroll
        for (int v = 0; v < VV; ++v) {
            const float4 M0 = mn[v * 6 + 0];
            const float4 M1 = mn[v * 6 + 1];
            const float4 M2 = mn[v * 6 + 2];
            const float4 N0 = mn[v * 6 + 3];
            const float4 N1 = mn[v * 6 + 4];
            const float4 N2 = mn[v * 6 + 5];

            const float x0 = fmaf(M0.x, X0, fmaf(M0.y, X1, fmaf(M0.z, X2, M0.w)));
            const float x1 = fmaf(M1.x, X0, fmaf(M1.y, X1, fmaf(M1.z, X2, M1.w)));
            const float x2 = fmaf(M2.x, X0, fmaf(M2.y, X1, fmaf(M2.z, X2, M2.w)));
            const float rg = __builtin_amdgcn_rcpf(x2);
            const float g0 = x0 * rg;
            const float g1 = x1 * rg;

            const float y0 = fmaf(N0.x, P0, fmaf(N0.y, P1, fmaf(N0.z, P2, N0.w)));
            const float y1 = fmaf(N1.x, P0, fmaf(N1.y, P1, fmaf(N1.z, P2, N1.w)));
            const float y2 = fmaf(N2.x, P0, fmaf(N2.y, P1, fmaf(N2.z, P2, N2.w)));
            const float rp = __builtin_amdgcn_rcpf(y2);
            const float q0 = y0 * rp;
            const float q1 = y1 * rp;

            float d0 = g0 - q0; d0 *= d0;
            float d1 = g1 - q1; d1 *= d1;
            // d^0.1 * 400^0.9 via v_log_f32 (log2) + v_exp_f32 (2^x)
            if (d0 > THR) d0 = __builtin_amdgcn_exp2f(ALPHA * __builtin_amdgcn_logf(d0)) * c09;
            if (d1 > THR) d1 = __builtin_amdgcn_exp2f(ALPHA * __builtin_amdgcn_logf(d1)) * c09;
            acc += d0 + d1;
        }

        __builtin_amdgcn_wave_barrier();  // fence: compute reads before next stage writes
    }

    // wave reduce + cross-wave reduce (single barrier)
#pragma unroll
    for (int off = 32; off > 0; off >>= 1)
        acc += __shfl_down(acc, off, 64);
    if (lane == 0) s_red[w] = acc;
    __syncthreads();
    if (tid == 0)
        partials[blockIdx.x] = s_red[0] + s_red[1] + s_red[2] + s_red[3];
}

// ---------------------------------------------------------------------------
// Final reduction of NB partials.
// ---------------------------------------------------------------------------
__global__ __launch_bounds__(256) void reduce_kernel(
    const float* __restrict__ partials, float* __restrict__ out, float scale)
{
    __shared__ float s_red[4];
    const int tid = threadIdx.x;
    float acc = 0.0f;
#pragma unroll
    for (int i = 0; i < NB / 256; ++i)
        acc += partials[tid + i * 256];
#pragma unroll
    for (int off = 32; off > 0; off >>= 1)
        acc += __shfl_down(acc, off, 64);
    const int wave = tid >> 6;
    const int lane = tid & 63;
    if (lane == 0) s_red[wave] = acc;
    __syncthreads();
    if (tid == 0)
        out[0] = (s_red[0] + s_red[1] + s_red[2] + s_red[3]) * scale;
}

extern "C" void kernel_launch(void* const* d_in, const int* in_sizes, int n_in,
                              void* d_out, int out_size, void* d_ws, size_t ws_size,
                              hipStream_t stream) {
    const float* kps_gt   = (const float*)d_in[0];
    const float* kps_pred = (const float*)d_in[1];
    const float* gt_R     = (const float*)d_in[2];
    const float* gt_t     = (const float*)d_in[3];
    const float* Kmat     = (const float*)d_in[4];
    const float* cam      = (const float*)d_in[5];
    float* out = (float*)d_out;
    float* partials = (float*)d_ws;

    const int B = in_sizes[0] / (JJ * 3);  // 16384
    const float scale = 1.0f / (2.0f * (float)B);
    (void)B;

    proj_loss_kernel<<<NB, 256, 0, stream>>>(kps_gt, kps_pred, gt_R, gt_t,
                                             Kmat, cam, partials);
    reduce_kernel<<<1, 256, 0, stream>>>(partials, out, scale);
}